// Round 17
// baseline (184.859 us; speedup 1.0000x reference)
//
#include <hip/hip_runtime.h>
#include <hip/hip_bf16.h>

// InputProjection: shared LayerNorm + Q/K/V projections (fp32 in, fp32 out).
// R17 = R11/R12 geometry with MERGED phases: one sync group per K32 tile
// (32 MFMA + 12 ds_read + 4 stage-loads + {lgkm0, vmcnt(4), barrier}) —
// halves the per-MFMA sync cost vs R11's 16-MFMA phases. Ledger: 4 regions
// [2buf][2kk]; phase p consumes tile p (region p%4), RDs tile p+1, stages
// tile p+3 into region (p+3)%4 (WAR: that region's reads drained 2 barriers
// ago). Steady vmcnt(4) = 2 stages in flight; prologue t0-t2 + vmcnt(4);
// tail 4/0/0.

#define HIDDEN 1024
#define NTOK   32768

typedef __bf16 bf16x8 __attribute__((ext_vector_type(8)));
typedef float  f32x4  __attribute__((ext_vector_type(4)));

#define GLOBAL_AS(p) ((const __attribute__((address_space(1))) void*)(p))
#define LDS_AS(p)    ((__attribute__((address_space(3))) void*)(p))

__device__ __forceinline__ unsigned short f2bf(float f) {
  union { float f; unsigned int i; } x; x.f = f;
  unsigned int r = x.i + 0x7FFFu + ((x.i >> 16) & 1u);   // RNE
  return (unsigned short)(r >> 16);
}

// ---------------- K1: LayerNorm (fp32 in, bf16 out) + weight cvt ----------------
__global__ __launch_bounds__(256) void ln_cvt_kernel(
    const float* __restrict__ x,
    const float* __restrict__ gamma,
    const float* __restrict__ beta,
    const float* __restrict__ wq,
    const float* __restrict__ wk,
    const float* __restrict__ wv,
    unsigned short* __restrict__ xn,
    unsigned short* __restrict__ wb) {
  const int bid = blockIdx.x;
  const int t   = threadIdx.x;
  if (bid < NTOK) {
    const size_t base = (size_t)bid * HIDDEN;
    const float4 v = ((const float4*)(x + base))[t];
    float s  = v.x + v.y + v.z + v.w;
    float s2 = v.x*v.x + v.y*v.y + v.z*v.z + v.w*v.w;
#pragma unroll
    for (int off = 32; off >= 1; off >>= 1) {
      s  += __shfl_xor(s,  off);
      s2 += __shfl_xor(s2, off);
    }
    __shared__ float red[8];
    const int w = t >> 6;
    if ((t & 63) == 0) { red[w] = s; red[4 + w] = s2; }
    __syncthreads();
    s  = red[0] + red[1] + red[2] + red[3];
    s2 = red[4] + red[5] + red[6] + red[7];
    const float mu   = s * (1.0f / HIDDEN);
    const float rstd = rsqrtf(s2 * (1.0f / HIDDEN) - mu * mu + 1e-5f);
    const float4 g  = ((const float4*)gamma)[t];
    const float4 bb = ((const float4*)beta)[t];
    ushort4 o;
    o.x = f2bf((v.x - mu) * rstd * g.x + bb.x);
    o.y = f2bf((v.y - mu) * rstd * g.y + bb.y);
    o.z = f2bf((v.z - mu) * rstd * g.z + bb.z);
    o.w = f2bf((v.w - mu) * rstd * g.w + bb.w);
    ((ushort4*)(xn + base))[t] = o;
  } else {
    const int b2 = bid - NTOK;           // 0..1535; 1024 wq, 256 wk, 256 wv
    const float* src;
    int off;
    if (b2 < 1024)      { src = wq; off = b2; }
    else if (b2 < 1280) { src = wk; off = b2 - 1024; }
    else                { src = wv; off = b2 - 1280; }
    const float4 v = ((const float4*)src)[off * 256 + t];
    ushort4 o;
    o.x = f2bf(v.x); o.y = f2bf(v.y); o.z = f2bf(v.z); o.w = f2bf(v.w);
    ((ushort4*)wb)[b2 * 256 + t] = o;
  }
}

// ---------------- K2: merged-phase QKV GEMM ----------------
// 768 blocks (128 M x 6 N), 512 threads (8 waves, 2M x 4N), wave tile 128x64.
__global__ __launch_bounds__(512, 2) void qkv_gemm(
    const unsigned short* __restrict__ xn,
    const unsigned short* __restrict__ wqb,
    const float* __restrict__ bq,
    const float* __restrict__ bk,
    const float* __restrict__ bv,
    float* __restrict__ out) {
  // 4 regions x [256 rows][32 k] bf16 per operand = 64 KiB each
  __shared__ unsigned short Alds[32768];
  __shared__ unsigned short Blds[32768];

  const int bid = blockIdx.x;
  const int swz = (bid & 7) * 96 + (bid >> 3);   // bijective: 768 % 8 == 0
  const int mt  = swz / 6;
  const int nt  = swz % 6;
  const int brow = mt * 256;

  const unsigned short* wbase; const float* biasptr;
  int segcol; size_t obase; int hg;
  if (nt < 4)       { wbase = wqb + (size_t)nt * 256 * HIDDEN;  biasptr = bq; segcol = nt * 256; obase = 0u;        hg = 16; }
  else if (nt == 4) { wbase = wqb + (size_t)1024 * HIDDEN;      biasptr = bk; segcol = 0;        obase = 33554432u; hg = 4;  }
  else              { wbase = wqb + (size_t)1280 * HIDDEN;      biasptr = bv; segcol = 0;        obase = 41943040u; hg = 4;  }

  const int t = threadIdx.x;
  const int w = t >> 6, lane = t & 63;
  const int wm = w >> 2, wn = w & 3;
  const int l15 = lane & 15, hi = lane >> 4;

  // staging (R9-proven): wave w rows 32w..32w+31; granule (lane&3)^((row>>1)&3)
  const int sr  = 2 * w * 16 + (lane >> 2);
  const int scg = ((lane & 3) ^ ((lane >> 3) & 3)) * 8;
  const unsigned short* aST = xn    + (size_t)(brow + sr) * HIDDEN + scg;
  const unsigned short* bST = wbase + (size_t)sr * HIDDEN + scg;
  const int ldsq = 2 * w * 512;   // wave-uniform; HW adds lane*16B

  // ds_read (R9-proven 0-conflict): addr = reg*8192 + row*32 + (hi^((row>>1)&3))*8
  const int rdx  = (hi ^ ((l15 >> 1) & 3)) * 8;
  const int rowA = wm * 128 + l15;
  const int rowB = wn * 64  + l15;

  f32x4 acc[8][4];
#pragma unroll
  for (int m = 0; m < 8; ++m)
#pragma unroll
    for (int n = 0; n < 4; ++n) acc[m][n] = (f32x4){0.f, 0.f, 0.f, 0.f};
  bf16x8 aC[8], bC[4], aN[8], bN[4];

// Region R (0..3) holds K32-tile p with p%4==R. ST covers this wave's 32-row
// slice of A and B (4 loads).
#define ST(R, KT) do {                                                          \
    unsigned short* _da = Alds + (R) * 8192 + ldsq;                             \
    unsigned short* _db = Blds + (R) * 8192 + ldsq;                             \
    const unsigned short* _sa = aST + (size_t)((KT) * 32);                      \
    const unsigned short* _sb = bST + (size_t)((KT) * 32);                      \
    __builtin_amdgcn_global_load_lds(GLOBAL_AS(_sa), LDS_AS(_da), 16, 0, 0);    \
    __builtin_amdgcn_global_load_lds(GLOBAL_AS(_sa + 16 * HIDDEN), LDS_AS(_da + 512), 16, 0, 0); \
    __builtin_amdgcn_global_load_lds(GLOBAL_AS(_sb), LDS_AS(_db), 16, 0, 0);    \
    __builtin_amdgcn_global_load_lds(GLOBAL_AS(_sb + 16 * HIDDEN), LDS_AS(_db + 512), 16, 0, 0); \
  } while (0)
#define RD(SA, SB, R) do { _Pragma("unroll")                                    \
    for (int m = 0; m < 8; ++m)                                                 \
      SA[m] = *(const bf16x8*)(Alds + (R) * 8192 + (rowA + m * 16) * 32 + rdx); \
    _Pragma("unroll")                                                           \
    for (int n = 0; n < 4; ++n)                                                 \
      SB[n] = *(const bf16x8*)(Blds + (R) * 8192 + (rowB + n * 16) * 32 + rdx); \
  } while (0)
#define MMX(SA, SB) do { _Pragma("unroll")                                      \
    for (int m = 0; m < 8; ++m)                                                 \
      _Pragma("unroll") for (int n = 0; n < 4; ++n)                             \
        acc[m][n] = __builtin_amdgcn_mfma_f32_16x16x32_bf16(SA[m], SB[n], acc[m][n], 0, 0, 0); \
  } while (0)
#define PIN __builtin_amdgcn_sched_barrier(0)
#define ENDPH(VMN) do {                                                         \
    asm volatile("s_waitcnt lgkmcnt(0)" ::: "memory");                          \
    asm volatile("s_waitcnt vmcnt(" #VMN ")" ::: "memory");                     \
    PIN; __builtin_amdgcn_s_barrier(); PIN;                                     \
  } while (0)

  // prologue: stage tiles 0,1,2 -> regions 0,1,2 (12 loads). vmcnt(4) drains
  // t0,t1 (t1 is RD'd during phase 0). Barrier; RD tile 0; lgkm0; barrier
  // (R11 race fix: all waves' t0 reads drain before phase-0 ST lands).
  ST(0, 0); ST(1, 1); ST(2, 2);
  asm volatile("s_waitcnt vmcnt(4)" ::: "memory");
  PIN; __builtin_amdgcn_s_barrier(); PIN;
  RD(aC, bC, 0);
  asm volatile("s_waitcnt lgkmcnt(0)" ::: "memory");
  PIN; __builtin_amdgcn_s_barrier(); PIN;

  // phases 0..27 (7 iters x 4). Phase p: ST(region (p+3)%4 <- tile p+3);
  // RD tile p+1; 32 MFMA tile p; lgkm0; vmcnt(4); barrier.
  for (int i = 0; i < 7; ++i) {
    const int T = 4 * i;
    /*p=T+0*/ ST(3, T + 3); RD(aN, bN, 1); PIN; MMX(aC, bC); ENDPH(4);
    /*p=T+1*/ ST(0, T + 4); RD(aC, bC, 2); PIN; MMX(aN, bN); ENDPH(4);
    /*p=T+2*/ ST(1, T + 5); RD(aN, bN, 3); PIN; MMX(aC, bC); ENDPH(4);
    /*p=T+3*/ ST(2, T + 6); RD(aC, bC, 0); PIN; MMX(aN, bN); ENDPH(4);
  }
  // p=28: last stage (t31 -> region 3). p=29/30: drains 0. p=31: final MFMA.
  /*p=28*/ ST(3, 31); RD(aN, bN, 1); PIN; MMX(aC, bC); ENDPH(4);
  /*p=29*/            RD(aC, bC, 2); PIN; MMX(aN, bN); ENDPH(0);
  /*p=30*/            RD(aN, bN, 3); PIN; MMX(aC, bC); ENDPH(0);
  /*p=31*/                                MMX(aN, bN);
  __builtin_amdgcn_s_barrier();   // all reads done before epilogue reuses LDS

#undef ST
#undef RD
#undef MMX
#undef ENDPH

  // ---- epilogue (R9-proven): wave output = contiguous [128 tok][64 d] fp32.
  // Per 16-token chunk: acc+bias -> LDS (stride 84, 2-way max) -> float4
  // reads -> 1KB-contiguous stores. Per-wave-disjoint LDS regions.
  float* ep = (float*)Alds;               // 8 waves x 16 x 84 f32 = 43008 B
  const int epb = w * 1344;
  const int headcol = segcol + wn * 64;
  const int gidx = headcol >> 6;
  const int tok0 = brow + wm * 128;
  const int b_ = tok0 >> 12;
  float* wout = out + obase + (size_t)(b_ * hg + gidx) * 262144u
                    + (size_t)(tok0 & 4095) * 64u;
  float biasv[4];
#pragma unroll
  for (int n = 0; n < 4; ++n) biasv[n] = biasptr[headcol + n * 16 + l15];

#pragma unroll
  for (int m = 0; m < 8; ++m) {
#pragma unroll
    for (int n = 0; n < 4; ++n)
#pragma unroll
      for (int j = 0; j < 4; ++j)
        ep[epb + (hi * 4 + j) * 84 + n * 16 + l15] = acc[m][n][j] + biasv[n];
    asm volatile("s_waitcnt lgkmcnt(0)" ::: "memory");
#pragma unroll
    for (int it = 0; it < 4; ++it) {
      const int r = it * 4 + hi;
      const float4 v = *(const float4*)(ep + epb + r * 84 + l15 * 4);
      *(float4*)(wout + (size_t)(m * 16 + r) * 64 + l15 * 4) = v;
    }
  }
#undef PIN
}

extern "C" void kernel_launch(void* const* d_in, const int* in_sizes, int n_in,
                              void* d_out, int out_size, void* d_ws, size_t ws_size,
                              hipStream_t stream) {
  const float* x  = (const float*)d_in[0];
  const float* wq = (const float*)d_in[1];
  const float* wk = (const float*)d_in[2];
  const float* wv = (const float*)d_in[3];
  const float* bq = (const float*)d_in[4];
  const float* bk = (const float*)d_in[5];
  const float* bv = (const float*)d_in[6];
  const float* g  = (const float*)d_in[7];
  const float* be = (const float*)d_in[8];
  float* out = (float*)d_out;

  unsigned short* xn = (unsigned short*)d_ws;                          // 64 MiB
  unsigned short* wb = (unsigned short*)((char*)d_ws + (64u << 20));   // 3 MiB (wq|wk|wv bf16)

  ln_cvt_kernel<<<NTOK + 1536, 256, 0, stream>>>(x, g, be, wq, wk, wv, xn, wb);
  qkv_gemm<<<768, 512, 0, stream>>>(xn, wb, bq, bk, bv, out);
}